// Round 2
// baseline (236.509 us; speedup 1.0000x reference)
//
#include <hip/hip_runtime.h>

// YOLO loss, round 8: wave-private LDS tiles, zero block barriers,
// all-loads-up-front for max memory-level parallelism.
//
// Evidence r6 vs r7: FETCH identical (72.4 MB) for scattered vs coalesced;
// r7 cut requests ~3x yet ran SLOWER (66 vs 59.6us) with occupancy 42% and
// phase barriers. Both stuck at ~1.2 TB/s with VALU <14%, Mfma 0 ->
// concurrency-bound (Little's law: BW = bytes-in-flight / latency), not
// bandwidth- or transaction-throughput-bound. r7's __syncthreads convoys
// killed overlap; r6 survived only via barrier-free waves.
//
// r8: keep r7's coalesced/gated loads, restore r6's free-running waves:
//  - each WAVE owns 64 cells and a private 7.7KB LDS slice; no
//    __syncthreads until the final block reduction.
//  - per wave, ALL global loads issue before any use: 8 gated dense
//    float4 (pred stage), 1 gated float4 (tbox), 5 gated transposed
//    float4 (tcls) = 14 in flight (~5x r6's effective MLP).
//  - mask gating via __shfl instead of LDS (smask gone).
// Predict: dur 66 -> 25-35us, FETCH ~70MB (floor), hbm_gbps ~2.5 TB/s,
// VALUBusy ~30%, occupancy ~50%.

#define SS 28
#define BLOCK 256
#define WAVES (BLOCK / 64)

__global__ __launch_bounds__(BLOCK) void yolo_main(
    const float4* __restrict__ pred4,   // [cells*30/4]
    const float4* __restrict__ tbox4,   // [cells]
    const float4* __restrict__ tcls4,   // [cells*5]
    const int*   __restrict__ mask,     // [cells]
    float4* __restrict__ block_part,    // [gridDim.x]
    int cells)
{
    __shared__ float  spred[WAVES][64 * 30];   // 4 x 7680 B = 30720 B
    __shared__ float4 sred[WAVES];

    const int tid    = threadIdx.x;
    const int lane   = tid & 63;
    const int wid    = tid >> 6;
    const int wcell0 = blockIdx.x * BLOCK + wid * 64;  // wave's first cell
    const int cell   = wcell0 + lane;

    int m = 0;
    if (cell < cells) m = mask[cell];                  // coalesced 4B

    // ---------------- issue ALL global loads up front ----------------
    // tbox: 16B stride across lanes (4 cells/line), gated on own mask
    float4 tb = make_float4(0.f, 0.f, 0.f, 0.f);
    if (m) tb = tbox4[cell];

    // pred: 480 dense float4 per wave (64 cells x 30 floats), gated at
    // float4 granularity. float4 p covers wave-floats [4p,4p+3]; a record
    // is 7.5 float4, so p can straddle cells c0,c3. Needed iff either
    // overlapping cell has mask=1, or it holds comp 4 / comp 9 of c0
    // (straddle part of c3 is comps 0..3 only, never 4/9).
    const size_t lim4 = (size_t)cells * 30 / 4;
    const size_t pb4  = (size_t)wcell0 * 30 / 4;
    float4 v[8];
    bool   nd[8];
    int    fo[8];
    #pragma unroll
    for (int it = 0; it < 8; ++it) {
        int p  = it * 64 + lane;            // 0..543, valid < 480
        int f0 = 4 * p;
        int c0 = f0 / 30;
        int c3 = (f0 + 3) / 30;
        int r0 = f0 - 30 * c0;
        int cc0 = c0 > 63 ? 63 : c0;        // clamp for uniform shfl
        int cc3 = c3 > 63 ? 63 : c3;
        int m0 = __shfl(m, cc0, 64);
        int m3 = __shfl(m, cc3, 64);
        bool need = (p < 480) && (pb4 + (size_t)p < lim4) &&
                    ((m0 | m3) || (r0 >= 1 && r0 <= 4) || (r0 >= 6 && r0 <= 9));
        nd[it] = need;
        fo[it] = f0;
        if (need) v[it] = pred4[pb4 + p];
    }

    // tcls: transposed, unit-stride float4 across lanes, gated per-lane
    // on owning cell's mask (OOB cells have m=0 -> gated off).
    const size_t tb4 = (size_t)wcell0 * 5;
    float4 t[5];
    bool   tn[5];
    int    tc[5], tk[5];
    #pragma unroll
    for (int it = 0; it < 5; ++it) {
        int q = it * 64 + lane;             // 0..319
        int c = q / 5;                      // 0..63
        int mc = __shfl(m, c, 64);
        tn[it] = mc != 0;
        tc[it] = c;
        tk[it] = q - 5 * c;
        if (mc) t[it] = tcls4[tb4 + q];
    }

    // ---------------- LDS stage (wave-private slice) ----------------
    float* sp = spred[wid];
    #pragma unroll
    for (int it = 0; it < 8; ++it) {
        if (nd[it]) *(float4*)(sp + fo[it]) = v[it];
    }
    // wave-scope: ensure the ds_writes have landed before cross-lane reads
    asm volatile("s_waitcnt lgkmcnt(0)" ::: "memory");

    float acc_cls = 0.f, acc_noobj = 0.f, acc_reg = 0.f, acc_cont = 0.f;

    // ---------------- per-cell compute (pred from own slice) ----------------
    if (cell < cells) {
        const float* pr = sp + lane * 30;
        if (!m) {
            float c1 = pr[4], c2 = pr[9];
            acc_noobj = c1 * c1 + c2 * c2;          // *0.5 in finalize
        } else {
            const float invS = 1.f / 28.f;
            float txc = tb.x * invS, tyc = tb.y * invS;
            float t0 = txc - 0.5f * tb.z, t1 = tyc - 0.5f * tb.w;
            float t2 = txc + 0.5f * tb.z, t3 = tyc + 0.5f * tb.w;
            float ta = (t2 - t0) * (t3 - t1);

            float b1xc = pr[0] * invS, b1yc = pr[1] * invS;
            float a0 = b1xc - 0.5f * pr[2], a1 = b1yc - 0.5f * pr[3];
            float a2 = b1xc + 0.5f * pr[2], a3 = b1yc + 0.5f * pr[3];
            float wx = fmaxf(fminf(a2, t2) - fmaxf(a0, t0), 0.f);
            float wy = fmaxf(fminf(a3, t3) - fmaxf(a1, t1), 0.f);
            float inter = wx * wy;
            float area1 = (a2 - a0) * (a3 - a1);
            float den = area1 + ta - inter;
            float iou1 = inter / (den > 0.f ? den : 1.f);

            float b2xc = pr[5] * invS, b2yc = pr[6] * invS;
            float c0 = b2xc - 0.5f * pr[7], c1 = b2yc - 0.5f * pr[8];
            float c2 = b2xc + 0.5f * pr[7], c3 = b2yc + 0.5f * pr[8];
            wx = fmaxf(fminf(c2, t2) - fmaxf(c0, t0), 0.f);
            wy = fmaxf(fminf(c3, t3) - fmaxf(c1, t1), 0.f);
            inter = wx * wy;
            float area2 = (c2 - c0) * (c3 - c1);
            den = area2 + ta - inter;
            float iou2 = inter / (den > 0.f ? den : 1.f);

            bool take1 = iou1 > iou2;
            float best_iou = take1 ? iou1 : iou2;
            float bbx = take1 ? pr[0] : pr[5];
            float bby = take1 ? pr[1] : pr[6];
            float bbw = take1 ? pr[2] : pr[7];
            float bbh = take1 ? pr[3] : pr[8];
            float bbc = take1 ? pr[4] : pr[9];

            float dx = bbx - tb.x, dy = bby - tb.y;
            float xy = dx * dx + dy * dy;

            float dw = sqrtf(bbw) - sqrtf(tb.z);    // mask==1: where() == value
            float dh = sqrtf(bbh) - sqrtf(tb.w);
            float wh = dw * dw + dh * dh;

            acc_reg = xy + wh;

            float dc = bbc - best_iou;
            acc_cont = dc * dc;
        }
    }

    // ---------------- cls loss (tcls regs vs LDS pred) ----------------
    #pragma unroll
    for (int it = 0; it < 5; ++it) {
        if (tn[it]) {
            const float* pp = sp + tc[it] * 30 + 10 + 4 * tk[it];
            float4 tt = t[it];
            float d0 = pp[0] - tt.x, d1 = pp[1] - tt.y;
            float d2 = pp[2] - tt.z, d3 = pp[3] - tt.w;
            acc_cls += d0 * d0 + d1 * d1 + d2 * d2 + d3 * d3;
        }
    }

    // ---------------- wave + block reduction ----------------
    float4 vr = make_float4(acc_cls, acc_noobj, acc_reg, acc_cont);
    #pragma unroll
    for (int off = 32; off >= 1; off >>= 1) {
        vr.x += __shfl_down(vr.x, off, 64);
        vr.y += __shfl_down(vr.y, off, 64);
        vr.z += __shfl_down(vr.z, off, 64);
        vr.w += __shfl_down(vr.w, off, 64);
    }
    if (lane == 0) sred[wid] = vr;
    __syncthreads();
    if (tid == 0) {
        float4 r = sred[0];
        #pragma unroll
        for (int w = 1; w < WAVES; ++w) {
            r.x += sred[w].x; r.y += sred[w].y; r.z += sred[w].z; r.w += sred[w].w;
        }
        block_part[blockIdx.x] = r;
    }
}

__global__ __launch_bounds__(BLOCK) void yolo_final(
    const float4* __restrict__ part, int nparts, float* __restrict__ out, float invN)
{
    float4 v = make_float4(0.f, 0.f, 0.f, 0.f);
    for (int i = threadIdx.x; i < nparts; i += BLOCK) {
        float4 p = part[i];
        v.x += p.x; v.y += p.y; v.z += p.z; v.w += p.w;
    }
    #pragma unroll
    for (int off = 32; off >= 1; off >>= 1) {
        v.x += __shfl_down(v.x, off, 64);
        v.y += __shfl_down(v.y, off, 64);
        v.z += __shfl_down(v.z, off, 64);
        v.w += __shfl_down(v.w, off, 64);
    }
    __shared__ float4 sred[BLOCK / 64];
    int lane = threadIdx.x & 63;
    int wave = threadIdx.x >> 6;
    if (lane == 0) sred[wave] = v;
    __syncthreads();
    if (threadIdx.x == 0) {
        float4 r = sred[0];
        #pragma unroll
        for (int w = 1; w < BLOCK / 64; ++w) {
            r.x += sred[w].x; r.y += sred[w].y; r.z += sred[w].z; r.w += sred[w].w;
        }
        float cls    = r.x;
        float no_obj = 0.5f * r.y;   // L_NOOBJ
        float reg    = 5.0f * r.z;   // L_COORD
        float cont   = r.w;
        float total  = cls + no_obj + cont + reg;
        out[0] = total  * invN;
        out[1] = reg    * invN;
        out[2] = cont   * invN;
        out[3] = no_obj * invN;
        out[4] = cls    * invN;
    }
}

extern "C" void kernel_launch(void* const* d_in, const int* in_sizes, int n_in,
                              void* d_out, int out_size, void* d_ws, size_t ws_size,
                              hipStream_t stream) {
    const float* pred = (const float*)d_in[0];
    const float* tbox = (const float*)d_in[1];
    const float* tcls = (const float*)d_in[2];
    const int*   mask = (const int*)d_in[3];
    float* out = (float*)d_out;

    int cells = in_sizes[0] / 30;                 // N*S*S = 802816
    int n_img = cells / (SS * SS);                // N
    int nblocks = (cells + BLOCK - 1) / BLOCK;    // 3136

    float4* part = (float4*)d_ws;                 // nblocks * 16 bytes

    yolo_main<<<nblocks, BLOCK, 0, stream>>>(
        (const float4*)pred, (const float4*)tbox, (const float4*)tcls,
        mask, part, cells);
    yolo_final<<<1, BLOCK, 0, stream>>>(part, nblocks, out, 1.0f / (float)n_img);
}

// Round 3
// 198.841 us; speedup vs baseline: 1.1894x; 1.1894x over previous
//
#include <hip/hip_runtime.h>

// YOLO loss, round 9: wave-private LDS staging via global_load_lds DMA.
//
// r8 post-mortem: predicted 25-35us, got 98us. Cause in counters:
// WRITE_SIZE 94MB (should be ~0) + FETCH +47MB = scratch spill of the
// conditionally-written register arrays v[8]/t[5] (VGPR_Count=44 ->
// compiler put them in local memory; guide rule #20). BUT r8 proved the
// memory system sustains 2.26 TB/s at 45% occupancy with this access mix
// -> r6/r7's 1.25 TB/s was concurrency-starvation, theory stands.
//
// r9 = r8 minus the spill:
//  - pred staging via __builtin_amdgcn_global_load_lds width=16: async
//    global->LDS DMA, ZERO VGPRs, vmcnt-tracked. Dest rule (wave-uniform
//    base + lane*16B, m104/m173) matches our linear slice exactly.
//  - tcls in 5 NAMED float4s (no arrays -> no scratch), tbox 1 float4.
//  - same shfl-based float4-granularity gating (proven exact in r8).
//  - all 14 requests in flight before one vmcnt(0); no block barriers.
// Predict: WRITE ~0.1MB, FETCH ~73MB, localMem=0, occupancy ~60%,
// dur 22-32us at >=2.2 TB/s effective.

#define SS 28
#define BLOCK 256
#define WAVES (BLOCK / 64)

typedef const __attribute__((address_space(1))) void* as1cp;
typedef __attribute__((address_space(3))) void* as3p;

__global__ __launch_bounds__(BLOCK) void yolo_main(
    const float4* __restrict__ pred4,   // [cells*30/4]
    const float4* __restrict__ tbox4,   // [cells]
    const float4* __restrict__ tcls4,   // [cells*5]
    const int*   __restrict__ mask,     // [cells]
    float4* __restrict__ block_part,    // [gridDim.x]
    int cells)
{
    __shared__ float  spred[WAVES][64 * 30];   // 4 x 7680 B
    __shared__ float4 sred[WAVES];

    const int tid    = threadIdx.x;
    const int lane   = tid & 63;
    const int wid    = tid >> 6;
    const int wcell0 = blockIdx.x * BLOCK + wid * 64;  // wave's first cell
    const int cell   = wcell0 + lane;

    int m = 0;
    if (cell < cells) m = mask[cell];                  // coalesced 4B

    float* sp = spred[wid];
    const size_t pb4  = (size_t)wcell0 * 30 / 4;
    const size_t lim4 = (size_t)cells * 30 / 4;

    // ---- pred staging: 8 gated async DMA float4 loads, no VGPRs ----
    // float4 p covers wave-floats [4p,4p+3]; a record is 7.5 float4 so a
    // float4 can straddle cells c0,c3. Needed iff an overlapping cell has
    // mask=1, or it holds comp4/comp9 of c0 (r0 in {2,4} / {6,8}; the
    // straddle tail of c3 is comps 0..2 only). Verified exact in r8.
    #pragma unroll
    for (int it = 0; it < 8; ++it) {
        int p  = it * 64 + lane;            // 0..543, valid < 480
        int f0 = 4 * p;
        int c0 = f0 / 30;
        int c3 = (f0 + 3) / 30;
        int r0 = f0 - 30 * c0;
        int m0 = __shfl(m, c0 > 63 ? 63 : c0, 64);
        int m3 = __shfl(m, c3 > 63 ? 63 : c3, 64);
        bool need = (p < 480) && (pb4 + (size_t)p < lim4) &&
                    ((m0 | m3) || (r0 >= 1 && r0 <= 4) || (r0 >= 6 && r0 <= 9));
        if (need) {
            // dest: wave-uniform base; HW adds lane*16B -> float offset f0
            __builtin_amdgcn_global_load_lds(
                (as1cp)(pred4 + pb4 + p),
                (as3p)(sp + it * 256),
                16, 0, 0);
        }
    }

    // ---- tbox: per-lane float4 (4 cells/line), gated ----
    float4 tb = make_float4(0.f, 0.f, 0.f, 0.f);
    if (m) tb = tbox4[cell];

    // ---- tcls: transposed unit-stride float4, 5 NAMED slots (no arrays) ----
    const size_t tq0 = (size_t)wcell0 * 5;
    float4 t0v, t1v, t2v, t3v, t4v;
    int n0, n1, n2, n3, n4;
    int c0_, c1_, c2_, c3_, c4_;
    int k0_, k1_, k2_, k3_, k4_;
#define TCLS_ISSUE(I, TT, NN, CC, KK)                            \
    {                                                            \
        int q = (I) * 64 + lane;                                 \
        int c = q / 5;                                           \
        int k = q - 5 * c;                                       \
        int mc = __shfl(m, c, 64);                               \
        NN = mc; CC = c; KK = k;                                 \
        TT = make_float4(0.f, 0.f, 0.f, 0.f);                    \
        if (mc) TT = tcls4[tq0 + q];                             \
    }
    TCLS_ISSUE(0, t0v, n0, c0_, k0_)
    TCLS_ISSUE(1, t1v, n1, c1_, k1_)
    TCLS_ISSUE(2, t2v, n2, c2_, k2_)
    TCLS_ISSUE(3, t3v, n3, c3_, k3_)
    TCLS_ISSUE(4, t4v, n4, c4_, k4_)
#undef TCLS_ISSUE

    // drain all 14 in-flight requests (global_load_lds is vmcnt-tracked)
    asm volatile("s_waitcnt vmcnt(0)" ::: "memory");
    __builtin_amdgcn_sched_barrier(0);

    float acc_cls = 0.f, acc_noobj = 0.f, acc_reg = 0.f, acc_cont = 0.f;

    // ---- per-cell compute (pred from own LDS slice) ----
    if (cell < cells) {
        const float* pr = sp + lane * 30;
        if (!m) {
            float c1 = pr[4], c2 = pr[9];
            acc_noobj = c1 * c1 + c2 * c2;          // *0.5 in finalize
        } else {
            const float invS = 1.f / 28.f;
            float txc = tb.x * invS, tyc = tb.y * invS;
            float t0 = txc - 0.5f * tb.z, t1 = tyc - 0.5f * tb.w;
            float t2 = txc + 0.5f * tb.z, t3 = tyc + 0.5f * tb.w;
            float ta = (t2 - t0) * (t3 - t1);

            float b1xc = pr[0] * invS, b1yc = pr[1] * invS;
            float a0 = b1xc - 0.5f * pr[2], a1 = b1yc - 0.5f * pr[3];
            float a2 = b1xc + 0.5f * pr[2], a3 = b1yc + 0.5f * pr[3];
            float wx = fmaxf(fminf(a2, t2) - fmaxf(a0, t0), 0.f);
            float wy = fmaxf(fminf(a3, t3) - fmaxf(a1, t1), 0.f);
            float inter = wx * wy;
            float area1 = (a2 - a0) * (a3 - a1);
            float den = area1 + ta - inter;
            float iou1 = inter / (den > 0.f ? den : 1.f);

            float b2xc = pr[5] * invS, b2yc = pr[6] * invS;
            float e0 = b2xc - 0.5f * pr[7], e1 = b2yc - 0.5f * pr[8];
            float e2 = b2xc + 0.5f * pr[7], e3 = b2yc + 0.5f * pr[8];
            wx = fmaxf(fminf(e2, t2) - fmaxf(e0, t0), 0.f);
            wy = fmaxf(fminf(e3, t3) - fmaxf(e1, t1), 0.f);
            inter = wx * wy;
            float area2 = (e2 - e0) * (e3 - e1);
            den = area2 + ta - inter;
            float iou2 = inter / (den > 0.f ? den : 1.f);

            bool take1 = iou1 > iou2;
            float best_iou = take1 ? iou1 : iou2;
            float bbx = take1 ? pr[0] : pr[5];
            float bby = take1 ? pr[1] : pr[6];
            float bbw = take1 ? pr[2] : pr[7];
            float bbh = take1 ? pr[3] : pr[8];
            float bbc = take1 ? pr[4] : pr[9];

            float dx = bbx - tb.x, dy = bby - tb.y;
            float xy = dx * dx + dy * dy;

            float dw = sqrtf(bbw) - sqrtf(tb.z);    // mask==1: where() == value
            float dh = sqrtf(bbh) - sqrtf(tb.w);
            float wh = dw * dw + dh * dh;

            acc_reg = xy + wh;

            float dc = bbc - best_iou;
            acc_cont = dc * dc;
        }
    }

    // ---- cls loss (tcls regs vs LDS pred) ----
#define TCLS_USE(TT, NN, CC, KK)                                  \
    if (NN) {                                                     \
        const float* pp = sp + CC * 30 + 10 + 4 * KK;             \
        float d0 = pp[0] - TT.x, d1 = pp[1] - TT.y;               \
        float d2 = pp[2] - TT.z, d3 = pp[3] - TT.w;               \
        acc_cls += d0 * d0 + d1 * d1 + d2 * d2 + d3 * d3;         \
    }
    TCLS_USE(t0v, n0, c0_, k0_)
    TCLS_USE(t1v, n1, c1_, k1_)
    TCLS_USE(t2v, n2, c2_, k2_)
    TCLS_USE(t3v, n3, c3_, k3_)
    TCLS_USE(t4v, n4, c4_, k4_)
#undef TCLS_USE

    // ---- wave + block reduction ----
    float4 vr = make_float4(acc_cls, acc_noobj, acc_reg, acc_cont);
    #pragma unroll
    for (int off = 32; off >= 1; off >>= 1) {
        vr.x += __shfl_down(vr.x, off, 64);
        vr.y += __shfl_down(vr.y, off, 64);
        vr.z += __shfl_down(vr.z, off, 64);
        vr.w += __shfl_down(vr.w, off, 64);
    }
    if (lane == 0) sred[wid] = vr;
    __syncthreads();
    if (tid == 0) {
        float4 r = sred[0];
        #pragma unroll
        for (int w = 1; w < WAVES; ++w) {
            r.x += sred[w].x; r.y += sred[w].y; r.z += sred[w].z; r.w += sred[w].w;
        }
        block_part[blockIdx.x] = r;
    }
}

__global__ __launch_bounds__(BLOCK) void yolo_final(
    const float4* __restrict__ part, int nparts, float* __restrict__ out, float invN)
{
    float4 v = make_float4(0.f, 0.f, 0.f, 0.f);
    for (int i = threadIdx.x; i < nparts; i += BLOCK) {
        float4 p = part[i];
        v.x += p.x; v.y += p.y; v.z += p.z; v.w += p.w;
    }
    #pragma unroll
    for (int off = 32; off >= 1; off >>= 1) {
        v.x += __shfl_down(v.x, off, 64);
        v.y += __shfl_down(v.y, off, 64);
        v.z += __shfl_down(v.z, off, 64);
        v.w += __shfl_down(v.w, off, 64);
    }
    __shared__ float4 sred[BLOCK / 64];
    int lane = threadIdx.x & 63;
    int wave = threadIdx.x >> 6;
    if (lane == 0) sred[wave] = v;
    __syncthreads();
    if (threadIdx.x == 0) {
        float4 r = sred[0];
        #pragma unroll
        for (int w = 1; w < BLOCK / 64; ++w) {
            r.x += sred[w].x; r.y += sred[w].y; r.z += sred[w].z; r.w += sred[w].w;
        }
        float cls    = r.x;
        float no_obj = 0.5f * r.y;   // L_NOOBJ
        float reg    = 5.0f * r.z;   // L_COORD
        float cont   = r.w;
        float total  = cls + no_obj + cont + reg;
        out[0] = total  * invN;
        out[1] = reg    * invN;
        out[2] = cont   * invN;
        out[3] = no_obj * invN;
        out[4] = cls    * invN;
    }
}

extern "C" void kernel_launch(void* const* d_in, const int* in_sizes, int n_in,
                              void* d_out, int out_size, void* d_ws, size_t ws_size,
                              hipStream_t stream) {
    const float* pred = (const float*)d_in[0];
    const float* tbox = (const float*)d_in[1];
    const float* tcls = (const float*)d_in[2];
    const int*   mask = (const int*)d_in[3];
    float* out = (float*)d_out;

    int cells = in_sizes[0] / 30;                 // N*S*S = 802816
    int n_img = cells / (SS * SS);                // N
    int nblocks = (cells + BLOCK - 1) / BLOCK;    // 3136

    float4* part = (float4*)d_ws;                 // nblocks * 16 bytes

    yolo_main<<<nblocks, BLOCK, 0, stream>>>(
        (const float4*)pred, (const float4*)tbox, (const float4*)tcls,
        mask, part, cells);
    yolo_final<<<1, BLOCK, 0, stream>>>(part, nblocks, out, 1.0f / (float)n_img);
}

// Round 4
// 191.828 us; speedup vs baseline: 1.2329x; 1.0366x over previous
//
#include <hip/hip_runtime.h>

// YOLO loss, round 10: r9 + dense nontemporal tbox + NT hints. Final polish.
//
// Model from r6-r9 (8 measurements, 2 sessions): duration = effective HBM
// BURST bytes / ~2.55 TB/s, invariant to every CU-side knob (coalescing,
// MLP, occupancy, barriers: r6 scattered 57%-occ and r9 DMA 38%-occ are
// bit-identical at 59.6/59.5us, same FETCH). FETCH_SIZE counts requested
// bytes; sparse 16-32B requests move 64B bursts -> counted BW 1.25 TB/s
// understates real ~2.5. Effective demand r9 ~147 MB; floor ~137.5 MB
// (pred 90.7 irreducible: comps 4/9 of EVERY record are live for no_obj).
//
// r10 shaves the worst stream: tbox gated 16B-per-masked-cell = 64B burst
// per 16B counted (4x waste, 15.4 MB effective) -> DENSE sequential load
// (12.8 MB, perfectly coalesced 1KB/wave) + nontemporal on all read-once
// streams (no reuse -> L2 allocate is overhead).
// Predict: FETCH 72.4->~81.5 MB (tbox fully counted now), WRITE ~0.1 MB,
// dur 56-59us. If >=59.5: the 2.55 TB/s effective-burst cap stands ->
// ROOFLINE (input layout AoS 120B/80B records + random 30% mask makes
// the remaining burst waste intrinsic).

#define SS 28
#define BLOCK 256
#define WAVES (BLOCK / 64)

typedef const __attribute__((address_space(1))) void* as1cp;
typedef __attribute__((address_space(3))) void* as3p;
typedef float f32x4 __attribute__((ext_vector_type(4)));

__global__ __launch_bounds__(BLOCK) void yolo_main(
    const float4* __restrict__ pred4,   // [cells*30/4]
    const float4* __restrict__ tbox4,   // [cells]
    const float4* __restrict__ tcls4,   // [cells*5]
    const int*   __restrict__ mask,     // [cells]
    float4* __restrict__ block_part,    // [gridDim.x]
    int cells)
{
    __shared__ float  spred[WAVES][64 * 30];   // 4 x 7680 B
    __shared__ float4 sred[WAVES];

    const int tid    = threadIdx.x;
    const int lane   = tid & 63;
    const int wid    = tid >> 6;
    const int wcell0 = blockIdx.x * BLOCK + wid * 64;  // wave's first cell
    const int cell   = wcell0 + lane;

    int m = 0;
    if (cell < cells) m = __builtin_nontemporal_load(mask + cell);

    float* sp = spred[wid];
    const size_t pb4  = (size_t)wcell0 * 30 / 4;
    const size_t lim4 = (size_t)cells * 30 / 4;

    // ---- pred staging: 8 gated async DMA float4 loads, no VGPRs ----
    // (gating exact per r8/r9, absmax=0: mask=0 records keep only the two
    //  float4s containing comps 4 and 9 = one contiguous 32B chunk)
    #pragma unroll
    for (int it = 0; it < 8; ++it) {
        int p  = it * 64 + lane;            // 0..543, valid < 480
        int f0 = 4 * p;
        int c0 = f0 / 30;
        int c3 = (f0 + 3) / 30;
        int r0 = f0 - 30 * c0;
        int m0 = __shfl(m, c0 > 63 ? 63 : c0, 64);
        int m3 = __shfl(m, c3 > 63 ? 63 : c3, 64);
        bool need = (p < 480) && (pb4 + (size_t)p < lim4) &&
                    ((m0 | m3) || (r0 >= 1 && r0 <= 4) || (r0 >= 6 && r0 <= 9));
        if (need) {
            __builtin_amdgcn_global_load_lds(
                (as1cp)(pred4 + pb4 + p),
                (as3p)(sp + it * 256),
                16, 0, 0);
        }
    }

    // ---- tbox: DENSE sequential (1KB/wave), nontemporal ----
    float4 tb = make_float4(0.f, 0.f, 0.f, 0.f);
    if (cell < cells) {
        f32x4 tv = __builtin_nontemporal_load((const f32x4*)(tbox4 + cell));
        tb.x = tv[0]; tb.y = tv[1]; tb.z = tv[2]; tb.w = tv[3];
    }

    // ---- tcls: transposed unit-stride float4, gated, NT, 5 named slots ----
    const size_t tq0 = (size_t)wcell0 * 5;
    float4 t0v, t1v, t2v, t3v, t4v;
    int n0, n1, n2, n3, n4;
    int c0_, c1_, c2_, c3_, c4_;
    int k0_, k1_, k2_, k3_, k4_;
#define TCLS_ISSUE(I, TT, NN, CC, KK)                                   \
    {                                                                   \
        int q = (I) * 64 + lane;                                        \
        int c = q / 5;                                                  \
        int k = q - 5 * c;                                              \
        int mc = __shfl(m, c, 64);                                      \
        NN = mc; CC = c; KK = k;                                        \
        TT = make_float4(0.f, 0.f, 0.f, 0.f);                           \
        if (mc) {                                                       \
            f32x4 tv = __builtin_nontemporal_load(                      \
                (const f32x4*)(tcls4 + tq0 + q));                       \
            TT.x = tv[0]; TT.y = tv[1]; TT.z = tv[2]; TT.w = tv[3];     \
        }                                                               \
    }
    TCLS_ISSUE(0, t0v, n0, c0_, k0_)
    TCLS_ISSUE(1, t1v, n1, c1_, k1_)
    TCLS_ISSUE(2, t2v, n2, c2_, k2_)
    TCLS_ISSUE(3, t3v, n3, c3_, k3_)
    TCLS_ISSUE(4, t4v, n4, c4_, k4_)
#undef TCLS_ISSUE

    // drain all in-flight requests (global_load_lds is vmcnt-tracked)
    asm volatile("s_waitcnt vmcnt(0)" ::: "memory");
    __builtin_amdgcn_sched_barrier(0);

    float acc_cls = 0.f, acc_noobj = 0.f, acc_reg = 0.f, acc_cont = 0.f;

    // ---- per-cell compute (pred from own LDS slice) ----
    if (cell < cells) {
        const float* pr = sp + lane * 30;
        if (!m) {
            float c1 = pr[4], c2 = pr[9];
            acc_noobj = c1 * c1 + c2 * c2;          // *0.5 in finalize
        } else {
            const float invS = 1.f / 28.f;
            float txc = tb.x * invS, tyc = tb.y * invS;
            float t0 = txc - 0.5f * tb.z, t1 = tyc - 0.5f * tb.w;
            float t2 = txc + 0.5f * tb.z, t3 = tyc + 0.5f * tb.w;
            float ta = (t2 - t0) * (t3 - t1);

            float b1xc = pr[0] * invS, b1yc = pr[1] * invS;
            float a0 = b1xc - 0.5f * pr[2], a1 = b1yc - 0.5f * pr[3];
            float a2 = b1xc + 0.5f * pr[2], a3 = b1yc + 0.5f * pr[3];
            float wx = fmaxf(fminf(a2, t2) - fmaxf(a0, t0), 0.f);
            float wy = fmaxf(fminf(a3, t3) - fmaxf(a1, t1), 0.f);
            float inter = wx * wy;
            float area1 = (a2 - a0) * (a3 - a1);
            float den = area1 + ta - inter;
            float iou1 = inter / (den > 0.f ? den : 1.f);

            float b2xc = pr[5] * invS, b2yc = pr[6] * invS;
            float e0 = b2xc - 0.5f * pr[7], e1 = b2yc - 0.5f * pr[8];
            float e2 = b2xc + 0.5f * pr[7], e3 = b2yc + 0.5f * pr[8];
            wx = fmaxf(fminf(e2, t2) - fmaxf(e0, t0), 0.f);
            wy = fmaxf(fminf(e3, t3) - fmaxf(e1, t1), 0.f);
            inter = wx * wy;
            float area2 = (e2 - e0) * (e3 - e1);
            den = area2 + ta - inter;
            float iou2 = inter / (den > 0.f ? den : 1.f);

            bool take1 = iou1 > iou2;
            float best_iou = take1 ? iou1 : iou2;
            float bbx = take1 ? pr[0] : pr[5];
            float bby = take1 ? pr[1] : pr[6];
            float bbw = take1 ? pr[2] : pr[7];
            float bbh = take1 ? pr[3] : pr[8];
            float bbc = take1 ? pr[4] : pr[9];

            float dx = bbx - tb.x, dy = bby - tb.y;
            float xy = dx * dx + dy * dy;

            float dw = sqrtf(bbw) - sqrtf(tb.z);    // mask==1: where() == value
            float dh = sqrtf(bbh) - sqrtf(tb.w);
            float wh = dw * dw + dh * dh;

            acc_reg = xy + wh;

            float dc = bbc - best_iou;
            acc_cont = dc * dc;
        }
    }

    // ---- cls loss (tcls regs vs LDS pred) ----
#define TCLS_USE(TT, NN, CC, KK)                                  \
    if (NN) {                                                     \
        const float* pp = sp + CC * 30 + 10 + 4 * KK;             \
        float d0 = pp[0] - TT.x, d1 = pp[1] - TT.y;               \
        float d2 = pp[2] - TT.z, d3 = pp[3] - TT.w;               \
        acc_cls += d0 * d0 + d1 * d1 + d2 * d2 + d3 * d3;         \
    }
    TCLS_USE(t0v, n0, c0_, k0_)
    TCLS_USE(t1v, n1, c1_, k1_)
    TCLS_USE(t2v, n2, c2_, k2_)
    TCLS_USE(t3v, n3, c3_, k3_)
    TCLS_USE(t4v, n4, c4_, k4_)
#undef TCLS_USE

    // ---- wave + block reduction ----
    float4 vr = make_float4(acc_cls, acc_noobj, acc_reg, acc_cont);
    #pragma unroll
    for (int off = 32; off >= 1; off >>= 1) {
        vr.x += __shfl_down(vr.x, off, 64);
        vr.y += __shfl_down(vr.y, off, 64);
        vr.z += __shfl_down(vr.z, off, 64);
        vr.w += __shfl_down(vr.w, off, 64);
    }
    if (lane == 0) sred[wid] = vr;
    __syncthreads();
    if (tid == 0) {
        float4 r = sred[0];
        #pragma unroll
        for (int w = 1; w < WAVES; ++w) {
            r.x += sred[w].x; r.y += sred[w].y; r.z += sred[w].z; r.w += sred[w].w;
        }
        block_part[blockIdx.x] = r;
    }
}

__global__ __launch_bounds__(BLOCK) void yolo_final(
    const float4* __restrict__ part, int nparts, float* __restrict__ out, float invN)
{
    float4 v = make_float4(0.f, 0.f, 0.f, 0.f);
    for (int i = threadIdx.x; i < nparts; i += BLOCK) {
        float4 p = part[i];
        v.x += p.x; v.y += p.y; v.z += p.z; v.w += p.w;
    }
    #pragma unroll
    for (int off = 32; off >= 1; off >>= 1) {
        v.x += __shfl_down(v.x, off, 64);
        v.y += __shfl_down(v.y, off, 64);
        v.z += __shfl_down(v.z, off, 64);
        v.w += __shfl_down(v.w, off, 64);
    }
    __shared__ float4 sred[BLOCK / 64];
    int lane = threadIdx.x & 63;
    int wave = threadIdx.x >> 6;
    if (lane == 0) sred[wave] = v;
    __syncthreads();
    if (threadIdx.x == 0) {
        float4 r = sred[0];
        #pragma unroll
        for (int w = 1; w < BLOCK / 64; ++w) {
            r.x += sred[w].x; r.y += sred[w].y; r.z += sred[w].z; r.w += sred[w].w;
        }
        float cls    = r.x;
        float no_obj = 0.5f * r.y;   // L_NOOBJ
        float reg    = 5.0f * r.z;   // L_COORD
        float cont   = r.w;
        float total  = cls + no_obj + cont + reg;
        out[0] = total  * invN;
        out[1] = reg    * invN;
        out[2] = cont   * invN;
        out[3] = no_obj * invN;
        out[4] = cls    * invN;
    }
}

extern "C" void kernel_launch(void* const* d_in, const int* in_sizes, int n_in,
                              void* d_out, int out_size, void* d_ws, size_t ws_size,
                              hipStream_t stream) {
    const float* pred = (const float*)d_in[0];
    const float* tbox = (const float*)d_in[1];
    const float* tcls = (const float*)d_in[2];
    const int*   mask = (const int*)d_in[3];
    float* out = (float*)d_out;

    int cells = in_sizes[0] / 30;                 // N*S*S = 802816
    int n_img = cells / (SS * SS);                // N
    int nblocks = (cells + BLOCK - 1) / BLOCK;    // 3136

    float4* part = (float4*)d_ws;                 // nblocks * 16 bytes

    yolo_main<<<nblocks, BLOCK, 0, stream>>>(
        (const float4*)pred, (const float4*)tbox, (const float4*)tcls,
        mask, part, cells);
    yolo_final<<<1, BLOCK, 0, stream>>>(part, nblocks, out, 1.0f / (float)n_img);
}